// Round 7
// baseline (1009.697 us; speedup 1.0000x reference)
//
#include <hip/hip_runtime.h>

// FeatureTokenizer — R7 DIAGNOSTIC ROUND.
// Kernel A (unchanged R4): writes the real 1 GiB output to d_out.
// Kernel B (probe): IDENTICAL structure (same loads, FMAs, store pattern)
// but writes a 3x-replicated output image into d_ws. B takes >460us so it
// enters the rocprof top-5, exposing hbm_gbps for ws-writes. This separates
// "d_out buffer is slow" from "our store pattern is slow":
//   B ~6.5 TB/s -> d_out write path is the ceiling; R4 was already roofline.
//   B ~4.6 TB/s -> pattern-limited; pursue wider per-thread stores.

typedef float fx4 __attribute__((ext_vector_type(4)));

constexpr int kB = 16384;
constexpr int kC = 128;
constexpr int kH = 128;
constexpr int kH4 = kH / 4;                    // 32 float4 per (b,c) row
constexpr int kTotal4 = kB * kC * kH4;         // 67,108,864 == 2^26
constexpr int kBlock = 256;
constexpr int kGrid = 2048;
constexpr int kStride4 = kGrid * kBlock;       // 524288 float4
constexpr int kIters = kTotal4 / kStride4;     // 128 (exact)
constexpr int kRcStep = kStride4 / kH4;        // 16384 rows (== 0 mod kC)

__global__ __launch_bounds__(kBlock) void FeatureTokenizer_69664369541889_kernel(
    const float* __restrict__ x, const float* __restrict__ m,
    const float* __restrict__ W, const float* __restrict__ bias,
    const float* __restrict__ me, float* __restrict__ out)
{
    const fx4* __restrict__ W4  = reinterpret_cast<const fx4*>(W);
    const fx4* __restrict__ b4  = reinterpret_cast<const fx4*>(bias);
    const fx4* __restrict__ me4 = reinterpret_cast<const fx4*>(me);
    fx4* __restrict__ out4      = reinterpret_cast<fx4*>(out);

    const int idx0 = blockIdx.x * kBlock + threadIdx.x;
    const int h4   = idx0 & (kH4 - 1);
    int rc         = idx0 >> 5;
    const int cc   = rc & (kC - 1);

    const fx4 w  = W4[cc * kH4 + h4];
    const fx4 bb = b4[cc * kH4 + h4];
    const fx4 e  = me4[h4];

    int oidx = idx0;
#pragma unroll 8
    for (int it = 0; it < kIters; ++it) {
        const float xv = x[rc];
        const float mv = m[rc];
        const float om = 1.0f - mv;
        fx4 o;
        o.x = fmaf(fmaf(xv, w.x, bb.x), om, e.x * mv);
        o.y = fmaf(fmaf(xv, w.y, bb.y), om, e.y * mv);
        o.z = fmaf(fmaf(xv, w.z, bb.z), om, e.z * mv);
        o.w = fmaf(fmaf(xv, w.w, bb.w), om, e.w * mv);
        out4[oidx] = o;
        rc   += kRcStep;
        oidx += kStride4;
    }
}

// Probe: same computation, replicated into d_ws (n4 fx4 slots, n4 multiple of
// kStride4 not required — guarded loop). Deterministic, pure scratch writes.
__global__ __launch_bounds__(kBlock) void ws_write_probe_kernel(
    const float* __restrict__ x, const float* __restrict__ m,
    const float* __restrict__ W, const float* __restrict__ bias,
    const float* __restrict__ me, fx4* __restrict__ ws, long long n4)
{
    const fx4* __restrict__ W4  = reinterpret_cast<const fx4*>(W);
    const fx4* __restrict__ b4  = reinterpret_cast<const fx4*>(bias);
    const fx4* __restrict__ me4 = reinterpret_cast<const fx4*>(me);

    const int idx0 = blockIdx.x * kBlock + threadIdx.x;
    const int h4   = idx0 & (kH4 - 1);
    const int cc   = (idx0 >> 5) & (kC - 1);   // invariant (strides divide C)

    const fx4 w  = W4[cc * kH4 + h4];
    const fx4 bb = b4[cc * kH4 + h4];
    const fx4 e  = me4[h4];

    for (long long idx = idx0; idx < n4; idx += kStride4) {
        const int rc = (int)((idx & (long long)(kTotal4 - 1)) >> 5);
        const float xv = x[rc];
        const float mv = m[rc];
        const float om = 1.0f - mv;
        fx4 o;
        o.x = fmaf(fmaf(xv, w.x, bb.x), om, e.x * mv);
        o.y = fmaf(fmaf(xv, w.y, bb.y), om, e.y * mv);
        o.z = fmaf(fmaf(xv, w.z, bb.z), om, e.z * mv);
        o.w = fmaf(fmaf(xv, w.w, bb.w), om, e.w * mv);
        ws[idx] = o;
    }
}

extern "C" void kernel_launch(void* const* d_in, const int* in_sizes, int n_in,
                              void* d_out, int out_size, void* d_ws, size_t ws_size,
                              hipStream_t stream) {
    const float* x    = (const float*)d_in[0];
    const float* m    = (const float*)d_in[1];
    const float* W    = (const float*)d_in[2];
    const float* bias = (const float*)d_in[3];
    const float* me   = (const float*)d_in[4];
    float* out        = (float*)d_out;

    // A: the real output (identical to R4).
    FeatureTokenizer_69664369541889_kernel<<<kGrid, kBlock, 0, stream>>>(
        x, m, W, bias, me, out);

    // B: 3-GiB probe into scratch (capped by ws_size).
    long long n4 = (long long)(ws_size / 16);
    const long long cap = 3LL * (long long)kTotal4;   // 3 GiB worth of fx4
    if (n4 > cap) n4 = cap;
    if (n4 > 0) {
        ws_write_probe_kernel<<<kGrid, kBlock, 0, stream>>>(
            x, m, W, bias, me, (fx4*)d_ws, n4);
    }
}